// Round 4
// baseline (100.288 us; speedup 1.0000x reference)
//
#include <hip/hip_runtime.h>
#include <hip/hip_bf16.h>

typedef __attribute__((ext_vector_type(8))) short bf16x8;
typedef __attribute__((ext_vector_type(4))) float f32x4;

__device__ __forceinline__ short f2b(float f) {
    __hip_bfloat16 h = __float2bfloat16(f);   // RNE
    return __builtin_bit_cast(short, h);
}

#define KT 256      // K-tile in floats (1 KB per row per stage)
#define NTILE 16    // 4096 / 256

// Kernel 1: x f32 -> bf16, and y2 = 2*(x @ A^T) as bf16.
__global__ void prep_kernel(const float* __restrict__ x,
                            const float* __restrict__ A,
                            ushort* __restrict__ xb,     // [64][4096] bf16
                            ushort* __restrict__ yb) {   // [64][64] bf16
    const int tid = threadIdx.x, bid = blockIdx.x;

    const int gid = bid * 256 + tid;
    if (gid < 65536) {
        float4 v = ((const float4*)x)[gid];
        ushort4 s;
        s.x = (ushort)f2b(v.x); s.y = (ushort)f2b(v.y);
        s.z = (ushort)f2b(v.z); s.w = (ushort)f2b(v.w);
        ((ushort4*)xb)[gid] = s;
    }

    const int wave = tid >> 6, lane = tid & 63;
    const int idx = bid * 4 + wave;          // 0..4095
    const int t = idx >> 6, r = idx & 63;
    const float4* xr = (const float4*)(x + (size_t)t * 4096);
    const float4* ar = (const float4*)(A + (size_t)r * 4096);
    float s = 0.f;
    #pragma unroll
    for (int i = 0; i < 16; ++i) {
        float4 a = xr[i * 64 + lane];
        float4 b = ar[i * 64 + lane];
        s += a.x * b.x + a.y * b.y + a.z * b.z + a.w * b.w;
    }
    #pragma unroll
    for (int off = 32; off; off >>= 1) s += __shfl_xor(s, off, 64);
    if (lane == 0) yb[idx] = (ushort)f2b(2.0f * s);
}

// Kernel 2: out[64][16384] = x@W^T + y2@B^T.
// 1024 blocks x 256 threads. Block owns 16 output cols (W rows j0..j0+15).
// W staged f32 into LDS in contiguous 1KB/row bursts, double-buffered,
// XOR-swizzled via pre-swizzled global source (rule #21).
// K-PHASE ROTATION: block b starts at tile (b & 15) and wraps, so the chip's
// instantaneous W-read offsets cover all 16 KB of row-span -> all HBM
// channels busy instead of phase-locked camping on one congruence class.
__global__ void __launch_bounds__(256)
lora_gemm(const float* __restrict__ W,      // [16384][4096]
          const float* __restrict__ Bm,     // [16384][64]
          const ushort* __restrict__ xb,    // [64][4096] bf16
          const ushort* __restrict__ yb,    // [64][64] bf16
          float* __restrict__ out) {        // [64][16384]
    __shared__ float lds[2][16 * KT];       // 2 x 16 KB

    const int tid  = threadIdx.x;
    const int w    = tid >> 6;              // wave 0..3 -> token group
    const int lane = tid & 63;
    const int c    = lane & 15;             // frag row/col index
    const int kg   = lane >> 4;             // k-group, offset kg*8
    const int j0   = blockIdx.x << 4;
    const int sw   = (c & 7) << 4;          // read-side swizzle
    const int t0   = blockIdx.x & 15;       // K-phase rotation start tile

    const ushort* xrow = xb + (size_t)(w * 16 + c) * 4096 + kg * 8;

    // wave w stages rows w*4 .. w*4+3 of the 16-row W panel (1 KB each).
    // LDS linear (gload_lds constraint); swizzle applied on the SOURCE:
    // LDS phys byte p holds W[row p/1024][colbyte (p%1024) ^ ((row&7)<<4)].
    auto stage = [&](float* dst, int kt) {
        #pragma unroll
        for (int q = 0; q < 4; ++q) {
            const int r = w * 4 + q;
            const int colb = (lane * 16) ^ ((r & 7) << 4);
            const char* src = (const char*)W +
                ((size_t)(j0 + r) * 4096 + (size_t)kt * KT) * 4 + colb;
            __builtin_amdgcn_global_load_lds((const uint32_t*)src,
                (uint32_t*)((char*)dst + r * 1024), 16, 0, 0);
        }
    };

    f32x4 acc = {0.f, 0.f, 0.f, 0.f};

    stage(lds[0], t0);
    __syncthreads();                         // drains vmcnt: buf0 ready

    for (int i = 0; i < NTILE; ++i) {
        const int t = (t0 + i) & 15;
        float* lbuf = lds[i & 1];
        if (i + 1 < NTILE) stage(lds[(i + 1) & 1], (t0 + i + 1) & 15);

        const char* lrow = (const char*)lbuf + c * 1024;
        #pragma unroll
        for (int s = 0; s < 8; ++s) {
            f32x4 b0 = *(const f32x4*)(lrow + s * 128 + ((kg * 32)      ^ sw));
            f32x4 b1 = *(const f32x4*)(lrow + s * 128 + ((kg * 32 + 16) ^ sw));
            bf16x8 bb;
            bb[0] = f2b(b0[0]); bb[1] = f2b(b0[1]);
            bb[2] = f2b(b0[2]); bb[3] = f2b(b0[3]);
            bb[4] = f2b(b1[0]); bb[5] = f2b(b1[1]);
            bb[6] = f2b(b1[2]); bb[7] = f2b(b1[3]);
            bf16x8 aa = *(const bf16x8*)(xrow + t * KT + s * 32);
            acc = __builtin_amdgcn_mfma_f32_16x16x32_bf16(aa, bb, acc, 0, 0, 0);
        }
        __syncthreads();                     // next buf landed; reads done
    }

    // lora tail: 2 K-steps over r=64 with B matrix and y2
    {
        const float*  br = Bm + (size_t)(j0 + c) * 64 + kg * 8;
        const ushort* y0 = yb + (size_t)(w * 16 + c) * 64 + kg * 8;
        #pragma unroll
        for (int k = 0; k < 64; k += 32) {
            f32x4 w0 = *(const f32x4*)(br + k);
            f32x4 w1 = *(const f32x4*)(br + k + 4);
            bf16x8 bb;
            bb[0] = f2b(w0[0]); bb[1] = f2b(w0[1]);
            bb[2] = f2b(w0[2]); bb[3] = f2b(w0[3]);
            bb[4] = f2b(w1[0]); bb[5] = f2b(w1[1]);
            bb[6] = f2b(w1[2]); bb[7] = f2b(w1[3]);
            bf16x8 aa = *(const bf16x8*)(y0 + k);
            acc = __builtin_amdgcn_mfma_f32_16x16x32_bf16(aa, bb, acc, 0, 0, 0);
        }
    }

    // store: token row = w*16 + kg*4 + r, col = j0 + c
    float* op = out + j0 + c;
    #pragma unroll
    for (int r = 0; r < 4; ++r)
        op[(size_t)(w * 16 + kg * 4 + r) * 16384] = acc[r];
}

extern "C" void kernel_launch(void* const* d_in, const int* in_sizes, int n_in,
                              void* d_out, int out_size, void* d_ws, size_t ws_size,
                              hipStream_t stream) {
    const float* x  = (const float*)d_in[0];
    const float* W  = (const float*)d_in[1];
    const float* A  = (const float*)d_in[2];
    const float* Bm = (const float*)d_in[3];
    float* out = (float*)d_out;

    ushort* xb = (ushort*)d_ws;                          // 64*4096*2 = 524288 B
    ushort* yb = (ushort*)((char*)d_ws + 524288);        // 64*64*2   = 8192 B

    prep_kernel<<<1024, 256, 0, stream>>>(x, A, xb, yb);
    lora_gemm<<<1024, 256, 0, stream>>>(W, Bm, xb, yb, out);
}

// Round 5
// 92.261 us; speedup vs baseline: 1.0870x; 1.0870x over previous
//
#include <hip/hip_runtime.h>
#include <hip/hip_bf16.h>

typedef __attribute__((ext_vector_type(8))) short bf16x8;
typedef __attribute__((ext_vector_type(4))) short s16x4;
typedef __attribute__((ext_vector_type(4))) float f32x4;

__device__ __forceinline__ short f2b(float f) {
    __hip_bfloat16 h = __float2bfloat16(f);   // RNE
    return __builtin_bit_cast(short, h);
}

#define KT 512      // K-tile in floats (2 KB/row f32, 1 KB/row bf16 in LDS)
#define NT 8        // 4096 / 512

// Kernel 1: x f32 -> bf16, and y2 = 2*(x @ A^T) as bf16.
__global__ void prep_kernel(const float* __restrict__ x,
                            const float* __restrict__ A,
                            ushort* __restrict__ xb,     // [64][4096] bf16
                            ushort* __restrict__ yb) {   // [64][64] bf16
    const int tid = threadIdx.x, bid = blockIdx.x;

    const int gid = bid * 256 + tid;
    if (gid < 65536) {
        float4 v = ((const float4*)x)[gid];
        ushort4 s;
        s.x = (ushort)f2b(v.x); s.y = (ushort)f2b(v.y);
        s.z = (ushort)f2b(v.z); s.w = (ushort)f2b(v.w);
        ((ushort4*)xb)[gid] = s;
    }

    const int wave = tid >> 6, lane = tid & 63;
    const int idx = bid * 4 + wave;          // 0..4095
    const int t = idx >> 6, r = idx & 63;
    const float4* xr = (const float4*)(x + (size_t)t * 4096);
    const float4* ar = (const float4*)(A + (size_t)r * 4096);
    float s = 0.f;
    #pragma unroll
    for (int i = 0; i < 16; ++i) {
        float4 a = xr[i * 64 + lane];
        float4 b = ar[i * 64 + lane];
        s += a.x * b.x + a.y * b.y + a.z * b.z + a.w * b.w;
    }
    #pragma unroll
    for (int off = 32; off; off >>= 1) s += __shfl_xor(s, off, 64);
    if (lane == 0) yb[idx] = (ushort)f2b(2.0f * s);
}

// Kernel 2: out[64][16384] = x@W^T + y2@B^T.
// 1024 blocks x 256 threads (4 waves). Block owns W rows j0..j0+15 (a
// CONTIGUOUS 256 KB region of W). T14 reg-staging:
//   issue lane-linear float4 loads for tile t+1  (coalescer-perfect)
//   ds_read(bf16, XOR-swizzled) + MFMA for tile t
//   [compiler vmcnt] cvt f32->bf16 in reg, ds_write swizzled -> buf[t+1]
//   one __syncthreads per tile (orders LDS only; HBM loads never drained
//   mid-idle -- they stay in flight under the whole MFMA phase).
__global__ void __launch_bounds__(256)
lora_gemm(const float* __restrict__ W,      // [16384][4096]
          const float* __restrict__ Bm,     // [16384][64]
          const ushort* __restrict__ xb,    // [64][4096] bf16
          const ushort* __restrict__ yb,    // [64][64] bf16
          float* __restrict__ out) {        // [64][16384]
    __shared__ ushort lds[2][16 * KT];      // 2 x 16 KB (bf16)

    const int tid  = threadIdx.x;
    const int w    = tid >> 6;              // wave 0..3 -> token group
    const int lane = tid & 63;
    const int c    = lane & 15;             // frag row/col index
    const int kg   = lane >> 4;             // k-group, offset kg*8
    const int j0   = blockIdx.x << 4;
    const int sx   = (c & 7) << 4;          // read-side swizzle

    const ushort* xrow = xb + (size_t)(w * 16 + c) * 4096 + kg * 8;

    f32x4 rg[4][2];                          // staged W: 4 rows x 2 chunks

    // wave w loads rows w*4..w*4+3; per row 2 chunks of 1 KB, lane-linear.
    auto load_tile = [&](int t) {
        #pragma unroll
        for (int q = 0; q < 4; ++q) {
            const float* src = W + (size_t)(j0 + w * 4 + q) * 4096
                                 + (size_t)t * KT + lane * 4;
            rg[q][0] = *(const f32x4*)(src);
            rg[q][1] = *(const f32x4*)(src + 256);
        }
    };
    // convert to bf16 and write XOR-swizzled (write-side swizzle is legal
    // with reg-staging; matches the read-side XOR below).
    auto write_tile = [&](int buf) {
        #pragma unroll
        for (int q = 0; q < 4; ++q) {
            const int r = w * 4 + q;
            char* rowb = (char*)&lds[buf][0] + r * 1024;
            #pragma unroll
            for (int h = 0; h < 2; ++h) {
                s16x4 p;
                p[0] = f2b(rg[q][h][0]); p[1] = f2b(rg[q][h][1]);
                p[2] = f2b(rg[q][h][2]); p[3] = f2b(rg[q][h][3]);
                *(s16x4*)(rowb + ((h * 512 + lane * 8) ^ ((r & 7) << 4))) = p;
            }
        }
    };

    f32x4 acc = {0.f, 0.f, 0.f, 0.f};

    load_tile(0);
    write_tile(0);
    __syncthreads();

    for (int t = 0; t < NT; ++t) {
        const int cur = t & 1;
        if (t + 1 < NT) load_tile(t + 1);    // in flight under MFMA phase

        const char* lrow = (const char*)&lds[cur][0] + c * 1024;
        #pragma unroll
        for (int s = 0; s < 16; ++s) {
            bf16x8 bb = *(const bf16x8*)(lrow + ((s * 64 + kg * 16) ^ sx));
            bf16x8 aa = *(const bf16x8*)(xrow + (size_t)t * KT + s * 32);
            acc = __builtin_amdgcn_mfma_f32_16x16x32_bf16(aa, bb, acc, 0, 0, 0);
        }

        if (t + 1 < NT) {
            write_tile(cur ^ 1);             // other buffer; last read at t-1,
            __syncthreads();                 // protected by t-1's barrier
        }
    }

    // lora tail: 2 K-steps over r=64 with B matrix and y2
    {
        const float*  br = Bm + (size_t)(j0 + c) * 64 + kg * 8;
        const ushort* y0 = yb + (size_t)(w * 16 + c) * 64 + kg * 8;
        #pragma unroll
        for (int k = 0; k < 64; k += 32) {
            f32x4 w0 = *(const f32x4*)(br + k);
            f32x4 w1 = *(const f32x4*)(br + k + 4);
            bf16x8 bb;
            bb[0] = f2b(w0[0]); bb[1] = f2b(w0[1]);
            bb[2] = f2b(w0[2]); bb[3] = f2b(w0[3]);
            bb[4] = f2b(w1[0]); bb[5] = f2b(w1[1]);
            bb[6] = f2b(w1[2]); bb[7] = f2b(w1[3]);
            bf16x8 aa = *(const bf16x8*)(y0 + k);
            acc = __builtin_amdgcn_mfma_f32_16x16x32_bf16(aa, bb, acc, 0, 0, 0);
        }
    }

    // store: token row = w*16 + kg*4 + r, col = j0 + c
    float* op = out + j0 + c;
    #pragma unroll
    for (int r = 0; r < 4; ++r)
        op[(size_t)(w * 16 + kg * 4 + r) * 16384] = acc[r];
}

extern "C" void kernel_launch(void* const* d_in, const int* in_sizes, int n_in,
                              void* d_out, int out_size, void* d_ws, size_t ws_size,
                              hipStream_t stream) {
    const float* x  = (const float*)d_in[0];
    const float* W  = (const float*)d_in[1];
    const float* A  = (const float*)d_in[2];
    const float* Bm = (const float*)d_in[3];
    float* out = (float*)d_out;

    ushort* xb = (ushort*)d_ws;                          // 64*4096*2 = 524288 B
    ushort* yb = (ushort*)((char*)d_ws + 524288);        // 64*64*2   = 8192 B

    prep_kernel<<<1024, 256, 0, stream>>>(x, A, xb, yb);
    lora_gemm<<<1024, 256, 0, stream>>>(W, Bm, xb, yb, out);
}